// Round 18
// baseline (582.230 us; speedup 1.0000x reference)
//
#include <hip/hip_runtime.h>
#include <math.h>

namespace {

constexpr int TNZ = 8, TNY = 512, TNX = 512, TM = 128;
constexpr int PITCH = 129;  // v2 pitch; 258 dw == 2 (mod 32) -> bank floor
constexpr float F0 = 1.0f / (TM * 0.2f);
constexpr float PK = -3.14159265358979323846f * 0.025f * 10.0f;
constexpr float PKF = PK * F0 * F0;  // phase = PKF * (iy^2 + ix^2)
constexpr float INV_N2 = 1.0f / (TM * TM);
constexpr float EPSV = 1e-10f;
constexpr float PIF = 3.14159265358979323846f;
constexpr float RT2H = 0.70710678118654752440f;

// packed float2 (lowers to v_pk_* VOP3P on gfx950)
typedef float v2 __attribute__((ext_vector_type(2)));
__device__ __forceinline__ v2 mk2(float x, float y) {
  v2 r; r.x = x; r.y = y; return r;
}

// compile-time-index unroll helper
template <int I> struct Ic { static constexpr int v = I; };
template <int I, int N, typename F>
__device__ __forceinline__ void u_impl(F&& f) {
  if constexpr (I < N) { f(Ic<I>{}); u_impl<I + 1, N>(f); }
}
template <int N, typename F>
__device__ __forceinline__ void u_for(F&& f) { u_impl<0, N>(f); }

// complex mul: (ar*br - ai*bi, ar*bi + ai*br) = pk_mul + pk_fma
__device__ __forceinline__ v2 cmul(v2 a, v2 b) {
  v2 p = a.xx * b;
  return __builtin_elementwise_fma(mk2(-a.y, a.y), b.yx, p);
}
// a * conj(b): (ar*br + ai*bi, ai*br - ar*bi)
__device__ __forceinline__ v2 cmulc(v2 a, v2 b) {
  v2 p = a.xx * mk2(b.x, -b.y);
  return __builtin_elementwise_fma(a.yy, b.yx, p);
}
__device__ __forceinline__ v2 fma2(float sg, v2 mine, v2 oth) {
  return __builtin_elementwise_fma(mk2(sg, sg), mine, oth);
}
// lane^1 / lane^2 exchange on the VALU pipe (DPP quad_perm; all 64 lanes)
template <int CTRL>
__device__ __forceinline__ float dppf(float v) {
  return __int_as_float(
      __builtin_amdgcn_mov_dpp(__float_as_int(v), CTRL, 0xF, 0xF, true));
}
template <int M>  // M = 1 or 2
__device__ __forceinline__ v2 shdpp(v2 v) {
  constexpr int CTRL = (M == 1) ? 0xB1 : 0x4E;
  return mk2(dppf<CTRL>(v.x), dppf<CTRL>(v.y));
}
// lane^4 / lane^8 exchange via explicit ds_swizzle (BitMode xor patterns)
template <int M>  // M = 4 or 8
__device__ __forceinline__ v2 shswz(v2 v) {
  constexpr int PAT = (M << 10) | 0x1F;
  return mk2(
      __int_as_float(__builtin_amdgcn_ds_swizzle(__float_as_int(v.x), PAT)),
      __int_as_float(__builtin_amdgcn_ds_swizzle(__float_as_int(v.y), PAT)));
}
__device__ __forceinline__ int rev7(int n) {
  return ((n & 1) << 6) | ((n & 2) << 4) | ((n & 4) << 2) | (n & 8) |
         ((n & 16) >> 2) | ((n & 32) >> 4) | ((n & 64) >> 6);
}
constexpr int crev3(int i) { return ((i & 1) << 2) | (i & 2) | ((i & 4) >> 2); }

// multiply by W8^i (literal): W8 = exp(-i*pi/4)
template <int i> __device__ __forceinline__ v2 mulW8(v2 t) {
  if constexpr (i == 0) return t;
  else if constexpr (i == 1) return (t + mk2(t.y, -t.x)) * RT2H;
  else if constexpr (i == 2) return mk2(t.y, -t.x);
  else return (mk2(t.y, -t.x) - t) * RT2H;
}
// multiply by conj(W8^i)
template <int i> __device__ __forceinline__ v2 mulW8c(v2 t) {
  if constexpr (i == 0) return t;
  else if constexpr (i == 1) return (t + mk2(-t.y, t.x)) * RT2H;
  else if constexpr (i == 2) return mk2(-t.y, t.x);
  else return (mk2(-t.y, t.x) - t) * RT2H;
}

struct Tw8 {
  v2 wq128, wq64, wq32;  // W128^q, W64^q, W32^q
  v2 ws8, ws4, ws2;      // upper-lane stage twiddles (lower lanes: 1)
  float sg8, sg4, sg2, sg1;  // butterfly signs per lane
};

// ---- FFT-128, ownership p = q + 16*i (q = lane&15, i = reg 0..7) ----
// DIF forward: natural position order in, bit-reversed order out.
__device__ __forceinline__ void dif8(v2 (&X)[8], const Tw8& T) {
  u_for<4>([&](auto I) {  // h=64 local: pairs (i, i+4); W = wq128 * W8^i
    constexpr int i = I.v;
    v2 A = X[i], B = X[i + 4];
    X[i] = A + B;
    X[i + 4] = mulW8<i>(cmul(A - B, T.wq128));
  });
  u_for<4>([&](auto I) {  // h=32 local: pairs (g, g+2); W = wq64 * W4^{g&1}
    constexpr int g = (I.v >> 1) * 4 + (I.v & 1);
    v2 A = X[g], B = X[g + 2];
    X[g] = A + B;
    v2 d = cmul(A - B, T.wq64);
    X[g + 2] = (g & 1) ? mk2(d.y, -d.x) : d;
  });
  u_for<4>([&](auto I) {  // h=16 local: pairs (e, e+1); W = wq32 (uniform)
    constexpr int e = I.v * 2;
    v2 A = X[e], B = X[e + 1];
    X[e] = A + B;
    X[e + 1] = cmul(A - B, T.wq32);
  });
  u_for<8>([&](auto I) {  // h=8 cross (mask 8, DS): W per-lane = ws8
    constexpr int i = I.v;
    v2 o = shswz<8>(X[i]);
    X[i] = cmul(fma2(T.sg8, X[i], o), T.ws8);
  });
  u_for<8>([&](auto I) {  // h=4 cross (mask 4, DS)
    constexpr int i = I.v;
    v2 o = shswz<4>(X[i]);
    X[i] = cmul(fma2(T.sg4, X[i], o), T.ws4);
  });
  u_for<8>([&](auto I) {  // h=2 cross (mask 2, DPP/VALU)
    constexpr int i = I.v;
    v2 o = shdpp<2>(X[i]);
    X[i] = cmul(fma2(T.sg2, X[i], o), T.ws2);
  });
  u_for<8>([&](auto I) {  // h=1 cross (mask 1, DPP/VALU): W = 1
    constexpr int i = I.v;
    v2 o = shdpp<1>(X[i]);
    X[i] = fma2(T.sg1, X[i], o);
  });
}

// Inverse (DIT): exact mirror network, conj twiddles; bitrev in, natural out.
__device__ __forceinline__ void dit8(v2 (&X)[8], const Tw8& T) {
  u_for<8>([&](auto I) {  // h=1 cross (DPP)
    constexpr int i = I.v;
    v2 o = shdpp<1>(X[i]);
    X[i] = fma2(T.sg1, X[i], o);
  });
  u_for<8>([&](auto I) {  // h=2 cross (DPP): u = mine*conj(ws2), exchange, fma
    constexpr int i = I.v;
    v2 u = cmulc(X[i], T.ws2);
    v2 o = shdpp<2>(u);
    X[i] = fma2(T.sg2, u, o);
  });
  u_for<8>([&](auto I) {  // h=4 cross (DS)
    constexpr int i = I.v;
    v2 u = cmulc(X[i], T.ws4);
    v2 o = shswz<4>(u);
    X[i] = fma2(T.sg4, u, o);
  });
  u_for<8>([&](auto I) {  // h=8 cross (DS)
    constexpr int i = I.v;
    v2 u = cmulc(X[i], T.ws8);
    v2 o = shswz<8>(u);
    X[i] = fma2(T.sg8, u, o);
  });
  u_for<4>([&](auto I) {  // h=16 local
    constexpr int e = I.v * 2;
    v2 A = X[e];
    v2 t = cmulc(X[e + 1], T.wq32);
    X[e] = A + t;
    X[e + 1] = A - t;
  });
  u_for<4>([&](auto I) {  // h=32 local: conj(W4^{g&1}) = +i for odd g
    constexpr int g = (I.v >> 1) * 4 + (I.v & 1);
    v2 A = X[g];
    v2 t0 = cmulc(X[g + 2], T.wq64);
    v2 t = (g & 1) ? mk2(-t0.y, t0.x) : t0;
    X[g] = A + t;
    X[g + 2] = A - t;
  });
  u_for<4>([&](auto I) {  // h=64 local: conj(W8^i) literal
    constexpr int i = I.v;
    v2 A = X[i];
    v2 t = mulW8c<i>(cmulc(X[i + 4], T.wq128));
    X[i] = A + t;
    X[i + 4] = A - t;
  });
}

// One block = one (k, mode). 512 threads: q = t&15, gg = t>>4 (0..31).
// Each thread runs FOUR independent row/col networks (y = gg + 32*h):
// 4x ILP on the FFT dependency chain, half the waves per barrier, and the
// 512-thread VGPR budget (128) holds the 32-v2 state without spill.
template <bool PRE>
__global__ __launch_bounds__(512)
void msp_mode(const float* __restrict__ V, const v2* __restrict__ Texp,
              const float* __restrict__ Pre, const float* __restrict__ Pim,
              const int* __restrict__ pos, float* __restrict__ out) {
  __shared__ v2 fld[TM * PITCH];  // 132,096 B field buffer (no swizzle)
  __shared__ v2 hyb[TM];  // hy at index 16i+q (bit-rev storage: conflict-free)
  __shared__ v2 hxb[TM];  // hx*INV_N2 at natural column index cc

  const int t = threadIdx.x;
  const int k = blockIdx.x >> 2;
  const int m = blockIdx.x & 3;
  const int q = t & 15;   // segment: owns positions q + 16*i
  const int gg = t >> 4;  // row/col group base, 0..31

  // per-thread twiddle constants
  Tw8 T;
  float s, c;
  const float qf = (float)q;
  __sincosf(-PIF * qf / 64.0f, &s, &c);  T.wq128 = mk2(c, s);
  __sincosf(-PIF * qf / 32.0f, &s, &c);  T.wq64  = mk2(c, s);
  __sincosf(-PIF * qf / 16.0f, &s, &c);  T.wq32  = mk2(c, s);
  if (q & 8) { __sincosf(-PIF * (float)(q & 7) / 8.0f, &s, &c); T.ws8 = mk2(c, s); }
  else T.ws8 = mk2(1.f, 0.f);
  if (q & 4) { __sincosf(-PIF * (float)(q & 3) / 4.0f, &s, &c); T.ws4 = mk2(c, s); }
  else T.ws4 = mk2(1.f, 0.f);
  T.ws2 = (q & 2) ? ((q & 1) ? mk2(0.f, -1.f) : mk2(1.f, 0.f)) : mk2(1.f, 0.f);
  T.sg8 = (q & 8) ? -1.f : 1.f;
  T.sg4 = (q & 4) ? -1.f : 1.f;
  T.sg2 = (q & 2) ? -1.f : 1.f;
  T.sg1 = (q & 1) ? -1.f : 1.f;

  const int rev4q =
      ((q & 1) << 3) | ((q & 2) << 1) | ((q & 4) >> 1) | ((q & 8) >> 3);

  // H tables (z-invariant): hyb[16i+q'] -> ky = 8*rev4(q') + rev3(i)
  if (t < TM) {
    const int qq = t & 15, ii = t >> 4;
    const int r4 = ((qq & 1) << 3) | ((qq & 2) << 1) | ((qq & 4) >> 1) |
                   ((qq & 8) >> 3);
    const int ky = 8 * r4 + crev3(ii);
    const int iy = ky - ((ky & 64) ? 128 : 0);
    float s0, c0;
    __sincosf(PKF * (float)(iy * iy), &s0, &c0);
    hyb[t] = mk2(c0, s0);
    const int kx = rev7(t);
    const int ixf = kx - ((kx & 64) ? 128 : 0);
    __sincosf(PKF * (float)(ixf * ixf), &s0, &c0);
    hxb[t] = mk2(c0 * INV_N2, s0 * INV_N2);
  }

  const int p0 = pos[2 * k];
  const int p1 = pos[2 * k + 1];

  // load probe mode m directly into the LDS field (4 row-groups)
  u_for<4>([&](auto H) {
    const int y = gg + 32 * H.v;
    const float* pr = Pre + (m * TM + y) * TM + q;
    const float* pi = Pim + (m * TM + y) * TM + q;
    u_for<8>([&](auto I) {
      constexpr int i = I.v;
      fld[y * PITCH + q + 16 * i] = mk2(pr[16 * i], pi[16 * i]);
    });
  });
  __syncthreads();

#pragma unroll 1
  for (int z = 0; z < TNZ; ++z) {
    // phase R (4 independent row networks): [rowI if z>0] -> T(z) -> rowF
    {
      v2 X[4][8];
      u_for<4>([&](auto H) {
        const int y = gg + 32 * H.v;
        u_for<8>([&](auto I) { X[H.v][I.v] = fld[y * PITCH + q + 16 * I.v]; });
      });
      if (z > 0) {
        u_for<4>([&](auto H) { dit8(X[H.v], T); });
      }
      u_for<4>([&](auto H) {
        const int y = gg + 32 * H.v;
        const int off = ((z * TNY) + (p0 + y)) * TNX + p1 + q;
        if constexpr (PRE) {
          const v2* tb = Texp + off;
          u_for<8>([&](auto I) { X[H.v][I.v] = cmul(X[H.v][I.v], tb[16 * I.v]); });
        } else {
          const float* vb = V + off;
          u_for<8>([&](auto I) {
            constexpr int i = I.v;
            float sv, cv;
            __sincosf(vb[16 * i], &sv, &cv);
            X[H.v][i] = cmul(X[H.v][i], mk2(cv, sv));
          });
        }
      });
      u_for<4>([&](auto H) { dif8(X[H.v], T); });
      u_for<4>([&](auto H) {
        const int y = gg + 32 * H.v;
        u_for<8>([&](auto I) { fld[y * PITCH + q + 16 * I.v] = X[H.v][I.v]; });
      });
    }
    __syncthreads();

    // phase C (4 independent col networks): colF -> [H -> colI] or |.|^2
    const bool last = (z == TNZ - 1);
    {
      v2 X[4][8];
      u_for<4>([&](auto H) {
        const int cc = gg + 32 * H.v;
        u_for<8>([&](auto I) { X[H.v][I.v] = fld[(q + 16 * I.v) * PITCH + cc]; });
      });
      u_for<4>([&](auto H) { dif8(X[H.v], T); });
      if (!last) {
        u_for<4>([&](auto H) {
          const int cc = gg + 32 * H.v;
          const v2 hxv = hxb[cc];
          u_for<8>([&](auto I) {  // H = hy[ky]*hx[kx]; INV_N2 folded in hx
            constexpr int i = I.v;
            X[H.v][i] = cmul(cmul(X[H.v][i], hyb[16 * i + q]), hxv);
          });
        });
        u_for<4>([&](auto H) { dit8(X[H.v], T); });
        u_for<4>([&](auto H) {
          const int cc = gg + 32 * H.v;
          u_for<8>([&](auto I) { fld[(q + 16 * I.v) * PITCH + cc] = X[H.v][I.v]; });
        });
      } else {
        // |psi_f|^2 scattered to natural frequency (ky,kx'), float view.
        // ky = 8*rev4q + rev3(i); kx' = rev7(cc) ^ rev4q (bank-spread XOR).
        float* fldf = reinterpret_cast<float*>(fld);
        u_for<4>([&](auto H) {
          const int cc = gg + 32 * H.v;
          const int kxn = rev7(cc) ^ rev4q;
          u_for<8>([&](auto I) {
            constexpr int i = I.v;
            const int ky = 8 * rev4q + crev3(i);
            float v = fmaf(X[H.v][i].x, X[H.v][i].x, X[H.v][i].y * X[H.v][i].y);
            fldf[ky * (2 * PITCH) + kxn] = v;
          });
        });
      }
    }
    __syncthreads();
  }

  // gather (linear, conflict-free, coalesced) and global atomic accumulate
  const float* fldf = reinterpret_cast<const float*>(fld);
  float* ob = out + k * (TM * TM);
#pragma unroll
  for (int ii = 0; ii < 32; ++ii) {
    const int idx = t + 512 * ii;
    const int ky = idx >> 7, kx = idx & 127;
    const int kxn = kx ^ ((ky >> 3) & 15);
    atomicAdd(&ob[idx], fldf[ky * (2 * PITCH) + kxn]);
  }
}

__global__ __launch_bounds__(256) void texp_k(const float* __restrict__ V,
                                              v2* __restrict__ Texp, int n) {
  const int i = blockIdx.x * 256 + threadIdx.x;
  if (i < n) {
    float s, c;
    __sincosf(V[i], &s, &c);
    Texp[i] = mk2(c, s);
  }
}

__global__ __launch_bounds__(256) void zero_k(float4* __restrict__ p, int n4) {
  const int i = blockIdx.x * 256 + threadIdx.x;
  if (i < n4) p[i] = make_float4(0.f, 0.f, 0.f, 0.f);
}

__global__ __launch_bounds__(256) void sqrt_k(float* __restrict__ p, int n) {
  const int i = blockIdx.x * 256 + threadIdx.x;
  if (i < n) p[i] = sqrtf(EPSV + p[i] * INV_N2);  // ortho: 1/N^2 on |.|^2
}

}  // namespace

extern "C" void kernel_launch(void* const* d_in, const int* in_sizes, int n_in,
                              void* d_out, int out_size, void* d_ws, size_t ws_size,
                              hipStream_t stream) {
  (void)in_sizes; (void)n_in;
  const float* V = (const float*)d_in[0];
  const float* Pre = (const float*)d_in[1];
  const float* Pim = (const float*)d_in[2];
  const int* pos = (const int*)d_in[3];
  float* out = (float*)d_out;
  const int n = out_size;  // 256*128*128
  const int n4 = n >> 2;
  zero_k<<<dim3((n4 + 255) / 256), dim3(256), 0, stream>>>((float4*)out, n4);

  const int nT = TNZ * TNY * TNX;
  const size_t texp_bytes = (size_t)nT * sizeof(v2);
  if (ws_size >= texp_bytes) {
    v2* Texp = (v2*)d_ws;
    texp_k<<<dim3((nT + 255) / 256), dim3(256), 0, stream>>>(V, Texp, nT);
    msp_mode<true><<<dim3(1024), dim3(512), 0, stream>>>(V, Texp, Pre, Pim,
                                                         pos, out);
  } else {
    msp_mode<false><<<dim3(1024), dim3(512), 0, stream>>>(V, nullptr, Pre,
                                                          Pim, pos, out);
  }
  sqrt_k<<<dim3((n + 255) / 256), dim3(256), 0, stream>>>(out, n);
}

// Round 19
// 577.171 us; speedup vs baseline: 1.0088x; 1.0088x over previous
//
#include <hip/hip_runtime.h>
#include <math.h>

namespace {

constexpr int TNZ = 8, TNY = 512, TNX = 512, TM = 128;
constexpr int PITCH = 129;  // v2 pitch; 258 dw == 2 (mod 32) -> bank floor
constexpr float F0 = 1.0f / (TM * 0.2f);
constexpr float PK = -3.14159265358979323846f * 0.025f * 10.0f;
constexpr float PKF = PK * F0 * F0;  // phase = PKF * (iy^2 + ix^2)
constexpr float INV_N2 = 1.0f / (TM * TM);
constexpr float EPSV = 1e-10f;
constexpr float PIF = 3.14159265358979323846f;
constexpr float RT2H = 0.70710678118654752440f;

// packed float2 (lowers to v_pk_* VOP3P on gfx950)
typedef float v2 __attribute__((ext_vector_type(2)));
__device__ __forceinline__ v2 mk2(float x, float y) {
  v2 r; r.x = x; r.y = y; return r;
}

// compile-time-index unroll helper
template <int I> struct Ic { static constexpr int v = I; };
template <int I, int N, typename F>
__device__ __forceinline__ void u_impl(F&& f) {
  if constexpr (I < N) { f(Ic<I>{}); u_impl<I + 1, N>(f); }
}
template <int N, typename F>
__device__ __forceinline__ void u_for(F&& f) { u_impl<0, N>(f); }

// complex mul: (ar*br - ai*bi, ar*bi + ai*br) = pk_mul + pk_fma
__device__ __forceinline__ v2 cmul(v2 a, v2 b) {
  v2 p = a.xx * b;
  return __builtin_elementwise_fma(mk2(-a.y, a.y), b.yx, p);
}
// a * conj(b): (ar*br + ai*bi, ai*br - ar*bi)
__device__ __forceinline__ v2 cmulc(v2 a, v2 b) {
  v2 p = a.xx * mk2(b.x, -b.y);
  return __builtin_elementwise_fma(a.yy, b.yx, p);
}
__device__ __forceinline__ v2 fma2(float sg, v2 mine, v2 oth) {
  return __builtin_elementwise_fma(mk2(sg, sg), mine, oth);
}
// lane^1 / lane^2 exchange on the VALU pipe (DPP quad_perm; all 64 lanes)
template <int CTRL>
__device__ __forceinline__ float dppf(float v) {
  return __int_as_float(
      __builtin_amdgcn_mov_dpp(__float_as_int(v), CTRL, 0xF, 0xF, true));
}
template <int M>  // M = 1 or 2
__device__ __forceinline__ v2 shdpp(v2 v) {
  constexpr int CTRL = (M == 1) ? 0xB1 : 0x4E;
  return mk2(dppf<CTRL>(v.x), dppf<CTRL>(v.y));
}
// lane^4 / lane^8 exchange via explicit ds_swizzle (BitMode xor patterns)
template <int M>  // M = 4 or 8
__device__ __forceinline__ v2 shswz(v2 v) {
  constexpr int PAT = (M << 10) | 0x1F;
  return mk2(
      __int_as_float(__builtin_amdgcn_ds_swizzle(__float_as_int(v.x), PAT)),
      __int_as_float(__builtin_amdgcn_ds_swizzle(__float_as_int(v.y), PAT)));
}
__device__ __forceinline__ int rev7(int n) {
  return ((n & 1) << 6) | ((n & 2) << 4) | ((n & 4) << 2) | (n & 8) |
         ((n & 16) >> 2) | ((n & 32) >> 4) | ((n & 64) >> 6);
}
constexpr int crev3(int i) { return ((i & 1) << 2) | (i & 2) | ((i & 4) >> 2); }

// multiply by W8^i (literal): W8 = exp(-i*pi/4)
template <int i> __device__ __forceinline__ v2 mulW8(v2 t) {
  if constexpr (i == 0) return t;
  else if constexpr (i == 1) return (t + mk2(t.y, -t.x)) * RT2H;
  else if constexpr (i == 2) return mk2(t.y, -t.x);
  else return (mk2(t.y, -t.x) - t) * RT2H;
}
// multiply by conj(W8^i)
template <int i> __device__ __forceinline__ v2 mulW8c(v2 t) {
  if constexpr (i == 0) return t;
  else if constexpr (i == 1) return (t + mk2(-t.y, t.x)) * RT2H;
  else if constexpr (i == 2) return mk2(-t.y, t.x);
  else return (mk2(-t.y, t.x) - t) * RT2H;
}

struct Tw8 {
  v2 wq128, wq64, wq32;  // W128^q, W64^q, W32^q
  v2 ws8, ws4, ws2;      // upper-lane stage twiddles (lower lanes: 1)
  float sg8, sg4, sg2, sg1;  // butterfly signs per lane
};

// ---- FFT-128, ownership p = q + 16*i (q = lane&15, i = reg 0..7) ----
// DIF forward: natural position order in, bit-reversed order out.
__device__ __forceinline__ void dif8(v2 (&X)[8], const Tw8& T) {
  u_for<4>([&](auto I) {  // h=64 local: pairs (i, i+4); W = wq128 * W8^i
    constexpr int i = I.v;
    v2 A = X[i], B = X[i + 4];
    X[i] = A + B;
    X[i + 4] = mulW8<i>(cmul(A - B, T.wq128));
  });
  u_for<4>([&](auto I) {  // h=32 local: pairs (g, g+2); W = wq64 * W4^{g&1}
    constexpr int g = (I.v >> 1) * 4 + (I.v & 1);
    v2 A = X[g], B = X[g + 2];
    X[g] = A + B;
    v2 d = cmul(A - B, T.wq64);
    X[g + 2] = (g & 1) ? mk2(d.y, -d.x) : d;
  });
  u_for<4>([&](auto I) {  // h=16 local: pairs (e, e+1); W = wq32 (uniform)
    constexpr int e = I.v * 2;
    v2 A = X[e], B = X[e + 1];
    X[e] = A + B;
    X[e + 1] = cmul(A - B, T.wq32);
  });
  u_for<8>([&](auto I) {  // h=8 cross (mask 8, DS): W per-lane = ws8
    constexpr int i = I.v;
    v2 o = shswz<8>(X[i]);
    X[i] = cmul(fma2(T.sg8, X[i], o), T.ws8);
  });
  u_for<8>([&](auto I) {  // h=4 cross (mask 4, DS)
    constexpr int i = I.v;
    v2 o = shswz<4>(X[i]);
    X[i] = cmul(fma2(T.sg4, X[i], o), T.ws4);
  });
  u_for<8>([&](auto I) {  // h=2 cross (mask 2, DPP/VALU)
    constexpr int i = I.v;
    v2 o = shdpp<2>(X[i]);
    X[i] = cmul(fma2(T.sg2, X[i], o), T.ws2);
  });
  u_for<8>([&](auto I) {  // h=1 cross (mask 1, DPP/VALU): W = 1
    constexpr int i = I.v;
    v2 o = shdpp<1>(X[i]);
    X[i] = fma2(T.sg1, X[i], o);
  });
}

// Inverse (DIT): exact mirror network, conj twiddles; bitrev in, natural out.
__device__ __forceinline__ void dit8(v2 (&X)[8], const Tw8& T) {
  u_for<8>([&](auto I) {  // h=1 cross (DPP)
    constexpr int i = I.v;
    v2 o = shdpp<1>(X[i]);
    X[i] = fma2(T.sg1, X[i], o);
  });
  u_for<8>([&](auto I) {  // h=2 cross (DPP): u = mine*conj(ws2), exchange, fma
    constexpr int i = I.v;
    v2 u = cmulc(X[i], T.ws2);
    v2 o = shdpp<2>(u);
    X[i] = fma2(T.sg2, u, o);
  });
  u_for<8>([&](auto I) {  // h=4 cross (DS)
    constexpr int i = I.v;
    v2 u = cmulc(X[i], T.ws4);
    v2 o = shswz<4>(u);
    X[i] = fma2(T.sg4, u, o);
  });
  u_for<8>([&](auto I) {  // h=8 cross (DS)
    constexpr int i = I.v;
    v2 u = cmulc(X[i], T.ws8);
    v2 o = shswz<8>(u);
    X[i] = fma2(T.sg8, u, o);
  });
  u_for<4>([&](auto I) {  // h=16 local
    constexpr int e = I.v * 2;
    v2 A = X[e];
    v2 t = cmulc(X[e + 1], T.wq32);
    X[e] = A + t;
    X[e + 1] = A - t;
  });
  u_for<4>([&](auto I) {  // h=32 local: conj(W4^{g&1}) = +i for odd g
    constexpr int g = (I.v >> 1) * 4 + (I.v & 1);
    v2 A = X[g];
    v2 t0 = cmulc(X[g + 2], T.wq64);
    v2 t = (g & 1) ? mk2(-t0.y, t0.x) : t0;
    X[g] = A + t;
    X[g + 2] = A - t;
  });
  u_for<4>([&](auto I) {  // h=64 local: conj(W8^i) literal
    constexpr int i = I.v;
    v2 A = X[i];
    v2 t = mulW8c<i>(cmulc(X[i + 4], T.wq128));
    X[i] = A + t;
    X[i + 4] = A - t;
  });
}

// One block = one k; modes looped in-block with register accumulation.
// 1024 threads: q = t&15, gg = t>>4. PRE: T=exp(iV) preloaded from d_ws.
template <bool PRE>
__global__ __launch_bounds__(1024)
void msp_k(const float* __restrict__ V, const v2* __restrict__ Texp,
           const float* __restrict__ Pre, const float* __restrict__ Pim,
           const int* __restrict__ pos, float* __restrict__ out) {
  __shared__ v2 fld[TM * PITCH];  // 132,096 B field buffer (no swizzle)
  __shared__ v2 hyb[TM];  // hy at index 16i+q (bit-rev storage: conflict-free)
  __shared__ v2 hxb[TM];  // hx*INV_N2 at natural column index cc

  const int t = threadIdx.x;
  const int k = blockIdx.x;
  const int q = t & 15;   // segment: owns positions q + 16*i
  const int gg = t >> 4;  // row (phase R) / col (phase C) group, 0..63

  // per-thread twiddle constants
  Tw8 T;
  float s, c;
  const float qf = (float)q;
  __sincosf(-PIF * qf / 64.0f, &s, &c);  T.wq128 = mk2(c, s);
  __sincosf(-PIF * qf / 32.0f, &s, &c);  T.wq64  = mk2(c, s);
  __sincosf(-PIF * qf / 16.0f, &s, &c);  T.wq32  = mk2(c, s);
  if (q & 8) { __sincosf(-PIF * (float)(q & 7) / 8.0f, &s, &c); T.ws8 = mk2(c, s); }
  else T.ws8 = mk2(1.f, 0.f);
  if (q & 4) { __sincosf(-PIF * (float)(q & 3) / 4.0f, &s, &c); T.ws4 = mk2(c, s); }
  else T.ws4 = mk2(1.f, 0.f);
  T.ws2 = (q & 2) ? ((q & 1) ? mk2(0.f, -1.f) : mk2(1.f, 0.f)) : mk2(1.f, 0.f);
  T.sg8 = (q & 8) ? -1.f : 1.f;
  T.sg4 = (q & 4) ? -1.f : 1.f;
  T.sg2 = (q & 2) ? -1.f : 1.f;
  T.sg1 = (q & 1) ? -1.f : 1.f;

  const int rev4q =
      ((q & 1) << 3) | ((q & 2) << 1) | ((q & 4) >> 1) | ((q & 8) >> 3);

  // H tables (z-invariant): hyb[16i+q'] -> ky = 8*rev4(q') + rev3(i)
  if (t < TM) {
    const int qq = t & 15, ii = t >> 4;
    const int r4 = ((qq & 1) << 3) | ((qq & 2) << 1) | ((qq & 4) >> 1) |
                   ((qq & 8) >> 3);
    const int ky = 8 * r4 + crev3(ii);
    const int iy = ky - ((ky & 64) ? 128 : 0);
    float s0, c0;
    __sincosf(PKF * (float)(iy * iy), &s0, &c0);
    hyb[t] = mk2(c0, s0);
    const int kx = rev7(t);
    const int ixf = kx - ((kx & 64) ? 128 : 0);
    __sincosf(PKF * (float)(ixf * ixf), &s0, &c0);
    hxb[t] = mk2(c0 * INV_N2, s0 * INV_N2);
  }

  const int p0 = pos[2 * k];
  const int p1 = pos[2 * k + 1];

  // |psi_f|^2 accumulator over modes: acc[i].x for h=0 col, .y for h=1 col
  v2 acc[8];
  u_for<8>([&](auto I) { acc[I.v] = mk2(0.f, 0.f); });

#pragma unroll 1
  for (int m = 0; m < 4; ++m) {
    // load probe mode m into the LDS field (previous mode's reads are done:
    // the z==7 end-of-iteration barrier protects fld)
#pragma unroll 1
    for (int h = 0; h < 2; ++h) {
      const int y = gg + 64 * h;
      const float* pr = Pre + (m * TM + y) * TM + q;
      const float* pi = Pim + (m * TM + y) * TM + q;
      u_for<8>([&](auto I) {
        constexpr int i = I.v;
        fld[y * PITCH + q + 16 * i] = mk2(pr[16 * i], pi[16 * i]);
      });
    }
    __syncthreads();

#pragma unroll 1
    for (int z = 0; z < TNZ; ++z) {
      // phase R: [rowI if z>0] -> T(z) -> rowF, per half
#pragma unroll 1
      for (int h = 0; h < 2; ++h) {
        const int y = gg + 64 * h;
        v2 X[8];
        u_for<8>([&](auto I) { X[I.v] = fld[y * PITCH + q + 16 * I.v]; });
        if (z > 0) dit8(X, T);
        const int off = ((z * TNY) + (p0 + y)) * TNX + p1 + q;
        if constexpr (PRE) {
          const v2* tb = Texp + off;
          u_for<8>([&](auto I) { X[I.v] = cmul(X[I.v], tb[16 * I.v]); });
        } else {
          const float* vb = V + off;
          u_for<8>([&](auto I) {
            constexpr int i = I.v;
            float v = vb[16 * i];
            float sv, cv;
            __sincosf(v, &sv, &cv);
            X[i] = cmul(X[i], mk2(cv, sv));
          });
        }
        dif8(X, T);
        u_for<8>([&](auto I) { fld[y * PITCH + q + 16 * I.v] = X[I.v]; });
      }
      __syncthreads();

      // phase C: colF -> [H -> colI] (z<7) or register-accumulate |.|^2
      const bool last = (z == TNZ - 1);
#pragma unroll 1
      for (int h = 0; h < 2; ++h) {
        const int cc = gg + 64 * h;
        v2 X[8];
        u_for<8>([&](auto I) { X[I.v] = fld[(q + 16 * I.v) * PITCH + cc]; });
        dif8(X, T);
        if (!last) {
          const v2 hxv = hxb[cc];  // broadcast within 16-lane groups
          u_for<8>([&](auto I) {   // H = hy[ky]*hx[kx]; INV_N2 folded in hx
            constexpr int i = I.v;
            X[i] = cmul(cmul(X[i], hyb[16 * i + q]), hxv);
          });
          dit8(X, T);
          u_for<8>([&](auto I) { fld[(q + 16 * I.v) * PITCH + cc] = X[I.v]; });
        } else {
          // accumulate in registers; NO LDS writes (race-free, no atomics)
          u_for<8>([&](auto I) {
            constexpr int i = I.v;
            float v = fmaf(X[i].x, X[i].x, X[i].y * X[i].y);
            if (h == 0) acc[i].x += v; else acc[i].y += v;
          });
        }
      }
      __syncthreads();  // z<7: cols ready; z==7: fld reads done -> reusable
    }
  }

  // scatter acc to natural frequency (ky,kx'), float view; bank-spread XOR
  float* fldf = reinterpret_cast<float*>(fld);
#pragma unroll 1
  for (int h = 0; h < 2; ++h) {
    const int cc = gg + 64 * h;
    const int kxn = rev7(cc) ^ rev4q;
    u_for<8>([&](auto I) {
      constexpr int i = I.v;
      const int ky = 8 * rev4q + crev3(i);
      fldf[ky * (2 * PITCH) + kxn] = (h == 0) ? acc[i].x : acc[i].y;
    });
  }
  __syncthreads();

  // gather (linear, conflict-free, coalesced), fused sqrt, plain store
  const float* cfldf = reinterpret_cast<const float*>(fld);
  float* ob = out + k * (TM * TM);
#pragma unroll
  for (int ii = 0; ii < 16; ++ii) {
    const int idx = t + 1024 * ii;
    const int ky = idx >> 7, kx = idx & 127;
    const int kxn = kx ^ ((ky >> 3) & 15);
    ob[idx] = sqrtf(EPSV + cfldf[ky * (2 * PITCH) + kxn] * INV_N2);
  }
}

__global__ __launch_bounds__(256) void texp_k(const float* __restrict__ V,
                                              v2* __restrict__ Texp, int n) {
  const int i = blockIdx.x * 256 + threadIdx.x;
  if (i < n) {
    float s, c;
    __sincosf(V[i], &s, &c);
    Texp[i] = mk2(c, s);
  }
}

}  // namespace

extern "C" void kernel_launch(void* const* d_in, const int* in_sizes, int n_in,
                              void* d_out, int out_size, void* d_ws, size_t ws_size,
                              hipStream_t stream) {
  (void)in_sizes; (void)n_in; (void)out_size;
  const float* V = (const float*)d_in[0];
  const float* Pre = (const float*)d_in[1];
  const float* Pim = (const float*)d_in[2];
  const int* pos = (const int*)d_in[3];
  float* out = (float*)d_out;

  const int nT = TNZ * TNY * TNX;
  const size_t texp_bytes = (size_t)nT * sizeof(v2);
  if (ws_size >= texp_bytes) {
    v2* Texp = (v2*)d_ws;
    texp_k<<<dim3((nT + 255) / 256), dim3(256), 0, stream>>>(V, Texp, nT);
    msp_k<true><<<dim3(256), dim3(1024), 0, stream>>>(V, Texp, Pre, Pim, pos,
                                                      out);
  } else {
    msp_k<false><<<dim3(256), dim3(1024), 0, stream>>>(V, nullptr, Pre, Pim,
                                                       pos, out);
  }
}

// Round 20
// 531.415 us; speedup vs baseline: 1.0956x; 1.0861x over previous
//
#include <hip/hip_runtime.h>
#include <math.h>

namespace {

constexpr int TNZ = 8, TNY = 512, TNX = 512, TM = 128;
constexpr int PITCH = 129;  // v2 pitch; 258 dw == 2 (mod 32) -> bank floor
constexpr float F0 = 1.0f / (TM * 0.2f);
constexpr float PK = -3.14159265358979323846f * 0.025f * 10.0f;
constexpr float PKF = PK * F0 * F0;  // phase = PKF * (iy^2 + ix^2)
constexpr float INV_N2 = 1.0f / (TM * TM);
constexpr float EPSV = 1e-10f;
constexpr float PIF = 3.14159265358979323846f;
constexpr float RT2H = 0.70710678118654752440f;

// packed float2 (lowers to v_pk_* VOP3P on gfx950)
typedef float v2 __attribute__((ext_vector_type(2)));
__device__ __forceinline__ v2 mk2(float x, float y) {
  v2 r; r.x = x; r.y = y; return r;
}

// compile-time-index unroll helper
template <int I> struct Ic { static constexpr int v = I; };
template <int I, int N, typename F>
__device__ __forceinline__ void u_impl(F&& f) {
  if constexpr (I < N) { f(Ic<I>{}); u_impl<I + 1, N>(f); }
}
template <int N, typename F>
__device__ __forceinline__ void u_for(F&& f) { u_impl<0, N>(f); }

// complex mul: (ar*br - ai*bi, ar*bi + ai*br) = pk_mul + pk_fma
__device__ __forceinline__ v2 cmul(v2 a, v2 b) {
  v2 p = a.xx * b;
  return __builtin_elementwise_fma(mk2(-a.y, a.y), b.yx, p);
}
// a * conj(b): (ar*br + ai*bi, ai*br - ar*bi)
__device__ __forceinline__ v2 cmulc(v2 a, v2 b) {
  v2 p = a.xx * mk2(b.x, -b.y);
  return __builtin_elementwise_fma(a.yy, b.yx, p);
}
__device__ __forceinline__ v2 fma2(float sg, v2 mine, v2 oth) {
  return __builtin_elementwise_fma(mk2(sg, sg), mine, oth);
}
// lane^1 / lane^2 exchange on the VALU pipe (DPP quad_perm; all 64 lanes)
template <int CTRL>
__device__ __forceinline__ float dppf(float v) {
  return __int_as_float(
      __builtin_amdgcn_mov_dpp(__float_as_int(v), CTRL, 0xF, 0xF, true));
}
template <int M>  // M = 1 or 2
__device__ __forceinline__ v2 shdpp(v2 v) {
  constexpr int CTRL = (M == 1) ? 0xB1 : 0x4E;
  return mk2(dppf<CTRL>(v.x), dppf<CTRL>(v.y));
}
// lane^4 / lane^8 exchange via explicit ds_swizzle (BitMode xor patterns)
template <int M>  // M = 4 or 8
__device__ __forceinline__ v2 shswz(v2 v) {
  constexpr int PAT = (M << 10) | 0x1F;
  return mk2(
      __int_as_float(__builtin_amdgcn_ds_swizzle(__float_as_int(v.x), PAT)),
      __int_as_float(__builtin_amdgcn_ds_swizzle(__float_as_int(v.y), PAT)));
}
__device__ __forceinline__ int rev7(int n) {
  return ((n & 1) << 6) | ((n & 2) << 4) | ((n & 4) << 2) | (n & 8) |
         ((n & 16) >> 2) | ((n & 32) >> 4) | ((n & 64) >> 6);
}
constexpr int crev3(int i) { return ((i & 1) << 2) | (i & 2) | ((i & 4) >> 2); }

// multiply by W8^i (literal): W8 = exp(-i*pi/4)
template <int i> __device__ __forceinline__ v2 mulW8(v2 t) {
  if constexpr (i == 0) return t;
  else if constexpr (i == 1) return (t + mk2(t.y, -t.x)) * RT2H;
  else if constexpr (i == 2) return mk2(t.y, -t.x);
  else return (mk2(t.y, -t.x) - t) * RT2H;
}
// multiply by conj(W8^i)
template <int i> __device__ __forceinline__ v2 mulW8c(v2 t) {
  if constexpr (i == 0) return t;
  else if constexpr (i == 1) return (t + mk2(-t.y, t.x)) * RT2H;
  else if constexpr (i == 2) return mk2(-t.y, t.x);
  else return (mk2(-t.y, t.x) - t) * RT2H;
}

struct Tw8 {
  v2 wq128, wq64, wq32;  // W128^q, W64^q, W32^q
  v2 ws8, ws4, ws2;      // upper-lane stage twiddles (lower lanes: 1)
  float sg8, sg4, sg2, sg1;  // butterfly signs per lane
};

// ---- FFT-128, ownership p = q + 16*i (q = lane&15, i = reg 0..7) ----
// DIF forward: natural position order in, bit-reversed order out.
__device__ __forceinline__ void dif8(v2 (&X)[8], const Tw8& T) {
  u_for<4>([&](auto I) {  // h=64 local: pairs (i, i+4); W = wq128 * W8^i
    constexpr int i = I.v;
    v2 A = X[i], B = X[i + 4];
    X[i] = A + B;
    X[i + 4] = mulW8<i>(cmul(A - B, T.wq128));
  });
  u_for<4>([&](auto I) {  // h=32 local: pairs (g, g+2); W = wq64 * W4^{g&1}
    constexpr int g = (I.v >> 1) * 4 + (I.v & 1);
    v2 A = X[g], B = X[g + 2];
    X[g] = A + B;
    v2 d = cmul(A - B, T.wq64);
    X[g + 2] = (g & 1) ? mk2(d.y, -d.x) : d;
  });
  u_for<4>([&](auto I) {  // h=16 local: pairs (e, e+1); W = wq32 (uniform)
    constexpr int e = I.v * 2;
    v2 A = X[e], B = X[e + 1];
    X[e] = A + B;
    X[e + 1] = cmul(A - B, T.wq32);
  });
  u_for<8>([&](auto I) {  // h=8 cross (mask 8, DS): W per-lane = ws8
    constexpr int i = I.v;
    v2 o = shswz<8>(X[i]);
    X[i] = cmul(fma2(T.sg8, X[i], o), T.ws8);
  });
  u_for<8>([&](auto I) {  // h=4 cross (mask 4, DS)
    constexpr int i = I.v;
    v2 o = shswz<4>(X[i]);
    X[i] = cmul(fma2(T.sg4, X[i], o), T.ws4);
  });
  u_for<8>([&](auto I) {  // h=2 cross (mask 2, DPP/VALU)
    constexpr int i = I.v;
    v2 o = shdpp<2>(X[i]);
    X[i] = cmul(fma2(T.sg2, X[i], o), T.ws2);
  });
  u_for<8>([&](auto I) {  // h=1 cross (mask 1, DPP/VALU): W = 1
    constexpr int i = I.v;
    v2 o = shdpp<1>(X[i]);
    X[i] = fma2(T.sg1, X[i], o);
  });
}

// Inverse (DIT): exact mirror network, conj twiddles; bitrev in, natural out.
__device__ __forceinline__ void dit8(v2 (&X)[8], const Tw8& T) {
  u_for<8>([&](auto I) {  // h=1 cross (DPP)
    constexpr int i = I.v;
    v2 o = shdpp<1>(X[i]);
    X[i] = fma2(T.sg1, X[i], o);
  });
  u_for<8>([&](auto I) {  // h=2 cross (DPP): u = mine*conj(ws2), exchange, fma
    constexpr int i = I.v;
    v2 u = cmulc(X[i], T.ws2);
    v2 o = shdpp<2>(u);
    X[i] = fma2(T.sg2, u, o);
  });
  u_for<8>([&](auto I) {  // h=4 cross (DS)
    constexpr int i = I.v;
    v2 u = cmulc(X[i], T.ws4);
    v2 o = shswz<4>(u);
    X[i] = fma2(T.sg4, u, o);
  });
  u_for<8>([&](auto I) {  // h=8 cross (DS)
    constexpr int i = I.v;
    v2 u = cmulc(X[i], T.ws8);
    v2 o = shswz<8>(u);
    X[i] = fma2(T.sg8, u, o);
  });
  u_for<4>([&](auto I) {  // h=16 local
    constexpr int e = I.v * 2;
    v2 A = X[e];
    v2 t = cmulc(X[e + 1], T.wq32);
    X[e] = A + t;
    X[e + 1] = A - t;
  });
  u_for<4>([&](auto I) {  // h=32 local: conj(W4^{g&1}) = +i for odd g
    constexpr int g = (I.v >> 1) * 4 + (I.v & 1);
    v2 A = X[g];
    v2 t0 = cmulc(X[g + 2], T.wq64);
    v2 t = (g & 1) ? mk2(-t0.y, t0.x) : t0;
    X[g] = A + t;
    X[g + 2] = A - t;
  });
  u_for<4>([&](auto I) {  // h=64 local: conj(W8^i) literal
    constexpr int i = I.v;
    v2 A = X[i];
    v2 t = mulW8c<i>(cmulc(X[i + 4], T.wq128));
    X[i] = A + t;
    X[i + 4] = A - t;
  });
}

// One block = one (k, mode). 1024 threads: q = t&15, gg = t>>4.
// PRE: T=exp(iV) preloaded from d_ws (else computed in-loop).
template <bool PRE>
__global__ __launch_bounds__(1024)
void msp_mode(const float* __restrict__ V, const v2* __restrict__ Texp,
              const float* __restrict__ Pre, const float* __restrict__ Pim,
              const int* __restrict__ pos, float* __restrict__ out) {
  __shared__ v2 fld[TM * PITCH];  // 132,096 B field buffer (no swizzle)
  __shared__ v2 hyb[TM];  // hy at index 16i+q (bit-rev storage: conflict-free)
  __shared__ v2 hxb[TM];  // hx*INV_N2 at natural column index cc

  const int t = threadIdx.x;
  const int k = blockIdx.x >> 2;
  const int m = blockIdx.x & 3;
  const int q = t & 15;   // segment: owns positions q + 16*i
  const int gg = t >> 4;  // row (phase R) / col (phase C) group, 0..63

  // per-thread twiddle constants
  Tw8 T;
  float s, c;
  const float qf = (float)q;
  __sincosf(-PIF * qf / 64.0f, &s, &c);  T.wq128 = mk2(c, s);
  __sincosf(-PIF * qf / 32.0f, &s, &c);  T.wq64  = mk2(c, s);
  __sincosf(-PIF * qf / 16.0f, &s, &c);  T.wq32  = mk2(c, s);
  if (q & 8) { __sincosf(-PIF * (float)(q & 7) / 8.0f, &s, &c); T.ws8 = mk2(c, s); }
  else T.ws8 = mk2(1.f, 0.f);
  if (q & 4) { __sincosf(-PIF * (float)(q & 3) / 4.0f, &s, &c); T.ws4 = mk2(c, s); }
  else T.ws4 = mk2(1.f, 0.f);
  T.ws2 = (q & 2) ? ((q & 1) ? mk2(0.f, -1.f) : mk2(1.f, 0.f)) : mk2(1.f, 0.f);
  T.sg8 = (q & 8) ? -1.f : 1.f;
  T.sg4 = (q & 4) ? -1.f : 1.f;
  T.sg2 = (q & 2) ? -1.f : 1.f;
  T.sg1 = (q & 1) ? -1.f : 1.f;

  const int rev4q =
      ((q & 1) << 3) | ((q & 2) << 1) | ((q & 4) >> 1) | ((q & 8) >> 3);

  // H tables (z-invariant): hyb[16i+q'] -> ky = 8*rev4(q') + rev3(i)
  if (t < TM) {
    const int qq = t & 15, ii = t >> 4;
    const int r4 = ((qq & 1) << 3) | ((qq & 2) << 1) | ((qq & 4) >> 1) |
                   ((qq & 8) >> 3);
    const int ky = 8 * r4 + crev3(ii);
    const int iy = ky - ((ky & 64) ? 128 : 0);
    float s0, c0;
    __sincosf(PKF * (float)(iy * iy), &s0, &c0);
    hyb[t] = mk2(c0, s0);
    const int kx = rev7(t);
    const int ixf = kx - ((kx & 64) ? 128 : 0);
    __sincosf(PKF * (float)(ixf * ixf), &s0, &c0);
    hxb[t] = mk2(c0 * INV_N2, s0 * INV_N2);
  }

  const int p0 = pos[2 * k];
  const int p1 = pos[2 * k + 1];

  // load probe mode m directly into the LDS field
#pragma unroll 1
  for (int h = 0; h < 2; ++h) {
    const int y = gg + 64 * h;
    const float* pr = Pre + (m * TM + y) * TM + q;
    const float* pi = Pim + (m * TM + y) * TM + q;
    u_for<8>([&](auto I) {
      constexpr int i = I.v;
      fld[y * PITCH + q + 16 * i] = mk2(pr[16 * i], pi[16 * i]);
    });
  }
  __syncthreads();

#pragma unroll 1
  for (int z = 0; z < TNZ; ++z) {
    // phase R: [rowI if z>0] -> T(z) -> rowF, per half
#pragma unroll 1
    for (int h = 0; h < 2; ++h) {
      const int y = gg + 64 * h;
      v2 X[8];
      u_for<8>([&](auto I) { X[I.v] = fld[y * PITCH + q + 16 * I.v]; });
      if (z > 0) dit8(X, T);
      const int off = ((z * TNY) + (p0 + y)) * TNX + p1 + q;
      if constexpr (PRE) {
        const v2* tb = Texp + off;
        u_for<8>([&](auto I) { X[I.v] = cmul(X[I.v], tb[16 * I.v]); });
      } else {
        const float* vb = V + off;
        u_for<8>([&](auto I) {
          constexpr int i = I.v;
          float v = vb[16 * i];
          float sv, cv;
          __sincosf(v, &sv, &cv);
          X[i] = cmul(X[i], mk2(cv, sv));
        });
      }
      dif8(X, T);
      u_for<8>([&](auto I) { fld[y * PITCH + q + 16 * I.v] = X[I.v]; });
    }
    __syncthreads();

    // phase C: colF -> [H -> colI] (or |.|^2 scatter on the last slice)
    const bool last = (z == TNZ - 1);
#pragma unroll 1
    for (int h = 0; h < 2; ++h) {
      const int cc = gg + 64 * h;
      v2 X[8];
      u_for<8>([&](auto I) { X[I.v] = fld[(q + 16 * I.v) * PITCH + cc]; });
      dif8(X, T);
      if (!last) {
        const v2 hxv = hxb[cc];  // broadcast within 16-lane groups
        u_for<8>([&](auto I) {   // H = hy[ky]*hx[kx]; INV_N2 folded in hx
          constexpr int i = I.v;
          X[i] = cmul(cmul(X[i], hyb[16 * i + q]), hxv);
        });
        dit8(X, T);
        u_for<8>([&](auto I) { fld[(q + 16 * I.v) * PITCH + cc] = X[I.v]; });
      } else {
        // |psi_f|^2 scattered to natural frequency (ky,kx'), float view.
        // ky = 8*rev4q + rev3(i); kx' = rev7(cc) ^ rev4q (bank-spread XOR).
        float* fldf = reinterpret_cast<float*>(fld);
        const int kxn = rev7(cc) ^ rev4q;
        u_for<8>([&](auto I) {
          constexpr int i = I.v;
          const int ky = 8 * rev4q + crev3(i);
          float v = fmaf(X[i].x, X[i].x, X[i].y * X[i].y);
          fldf[ky * (2 * PITCH) + kxn] = v;
        });
      }
    }
    __syncthreads();
  }

  // gather (linear, conflict-free, coalesced) and global atomic accumulate
  const float* fldf = reinterpret_cast<const float*>(fld);
  float* ob = out + k * (TM * TM);
#pragma unroll
  for (int ii = 0; ii < 16; ++ii) {
    const int idx = t + 1024 * ii;
    const int ky = idx >> 7, kx = idx & 127;
    const int kxn = kx ^ ((ky >> 3) & 15);
    atomicAdd(&ob[idx], fldf[ky * (2 * PITCH) + kxn]);
  }
}

__global__ __launch_bounds__(256) void texp_k(const float* __restrict__ V,
                                              v2* __restrict__ Texp, int n) {
  const int i = blockIdx.x * 256 + threadIdx.x;
  if (i < n) {
    float s, c;
    __sincosf(V[i], &s, &c);
    Texp[i] = mk2(c, s);
  }
}

__global__ __launch_bounds__(256) void zero_k(float4* __restrict__ p, int n4) {
  const int i = blockIdx.x * 256 + threadIdx.x;
  if (i < n4) p[i] = make_float4(0.f, 0.f, 0.f, 0.f);
}

__global__ __launch_bounds__(256) void sqrt_k(float* __restrict__ p, int n) {
  const int i = blockIdx.x * 256 + threadIdx.x;
  if (i < n) p[i] = sqrtf(EPSV + p[i] * INV_N2);  // ortho: 1/N^2 on |.|^2
}

}  // namespace

extern "C" void kernel_launch(void* const* d_in, const int* in_sizes, int n_in,
                              void* d_out, int out_size, void* d_ws, size_t ws_size,
                              hipStream_t stream) {
  (void)in_sizes; (void)n_in;
  const float* V = (const float*)d_in[0];
  const float* Pre = (const float*)d_in[1];
  const float* Pim = (const float*)d_in[2];
  const int* pos = (const int*)d_in[3];
  float* out = (float*)d_out;
  const int n = out_size;  // 256*128*128
  const int n4 = n >> 2;
  zero_k<<<dim3((n4 + 255) / 256), dim3(256), 0, stream>>>((float4*)out, n4);

  const int nT = TNZ * TNY * TNX;
  const size_t texp_bytes = (size_t)nT * sizeof(v2);
  if (ws_size >= texp_bytes) {
    v2* Texp = (v2*)d_ws;
    texp_k<<<dim3((nT + 255) / 256), dim3(256), 0, stream>>>(V, Texp, nT);
    msp_mode<true><<<dim3(1024), dim3(1024), 0, stream>>>(V, Texp, Pre, Pim,
                                                          pos, out);
  } else {
    msp_mode<false><<<dim3(1024), dim3(1024), 0, stream>>>(V, nullptr, Pre,
                                                           Pim, pos, out);
  }
  sqrt_k<<<dim3((n + 255) / 256), dim3(256), 0, stream>>>(out, n);
}